// Round 1
// baseline (85.249 us; speedup 1.0000x reference)
//
#include <hip/hip_runtime.h>
#include <hip/hip_bf16.h>
#include <cstdint>
#include <cstddef>

#define BSZ 16
#define NN  256
#define DE  64
#define DXX 256
#define IB  4   // rows (b,i) per block

// ---------------------------------------------------------------------------
// Prologue: normalize the boolean mask (unknown on-device representation:
// uint8 / int32 / float32) into 4096 floats (0.0/1.0) in workspace.
// Detection uses only the first 4096 bytes (safe under all three layouts):
//   int32 : bytes at pos%4 in {1,2,3} are all zero
//   f32   : bytes at pos%4==1 all zero, pos%4 in {2,3} nonzero (0x3f800000)
//   uint8 : nonzero bytes at all residues
// ---------------------------------------------------------------------------
__global__ void mask_prep(const uint8_t* __restrict__ raw, float* __restrict__ maskf) {
    __shared__ int s1_tot, s23_tot;
    int t = threadIdx.x;
    if (t == 0) { s1_tot = 0; s23_tot = 0; }
    __syncthreads();
    int s1 = 0, s23 = 0;
    {
        int base = t * 16;  // 256 threads * 16 bytes = 4096 bytes
        #pragma unroll
        for (int u = 0; u < 16; ++u) {
            int p = base + u;
            int v = (int)raw[p];
            int m4 = p & 3;
            if (m4 == 1) s1 += v;
            else if (m4 >= 2) s23 += v;
        }
    }
    atomicAdd(&s1_tot, s1);
    atomicAdd(&s23_tot, s23);
    __syncthreads();
    int kind = (s23_tot == 0) ? 1 : ((s1_tot == 0) ? 2 : 0);  // 0=u8, 1=i32, 2=f32
    for (int idx = t; idx < BSZ * NN; idx += 256) {
        float mv;
        if (kind == 1)      mv = (((const int*)(const void*)raw)[idx] != 0) ? 1.0f : 0.0f;
        else if (kind == 2) mv = (((const float*)(const void*)raw)[idx] != 0.0f) ? 1.0f : 0.0f;
        else                mv = (raw[idx] != 0) ? 1.0f : 0.0f;
        maskf[idx] = mv;
    }
}

// ---------------------------------------------------------------------------
// Main fused kernel: per block, IB=4 rows (b,i).
//   Phase 0: load mask row for batch b, count via ballot.
//   Phase 1: per row, one-pass reduction over j (sum, masked sum/sumsq,
//            masked min/max) -> z[256] in LDS.
//   Phase 2: out[row, dx] = sum_f z[f]*W[dx,f] + bias[dx], thread t = dx.
// ---------------------------------------------------------------------------
__global__ __launch_bounds__(256) void etox_main(
    const float* __restrict__ E, const float* __restrict__ maskf,
    const float* __restrict__ W, const float* __restrict__ bias,
    float* __restrict__ out)
{
    __shared__ float m_lds[NN];            // mask row (1 KB)
    __shared__ float cpart[4];
    __shared__ float partial[4][16][20];   // [wave][dquad][acc] 5 KB
    __shared__ float z_lds[IB][4 * DE];    // 4 KB

    const int t    = threadIdx.x;
    const int blk  = blockIdx.x;
    const int g0   = blk * IB;             // global row = b*NN + i
    const int b    = g0 >> 8;

    // ---- phase 0: mask + count ----
    float mv = maskf[b * NN + t];
    m_lds[t] = mv;
    unsigned long long bal = __ballot(mv != 0.0f);
    const int wv   = t >> 6;
    const int lane = t & 63;
    if (lane == 0) cpart[wv] = (float)__popcll(bal);
    __syncthreads();
    const float cnt = cpart[0] + cpart[1] + cpart[2] + cpart[3];
    const float inv_cnt = 1.0f / cnt;

    const int dq = t & 15;     // d-quad: d = 4*dq .. 4*dq+3
    const int jb = t >> 4;     // j-group: j = jb, jb+16, ...

    for (int r = 0; r < IB; ++r) {
        const float* Erow = E + (size_t)(g0 + r) * NN * DE;

        float s0=0.f,s1=0.f,s2=0.f,s3=0.f;           // unmasked sum
        float ms0=0.f,ms1=0.f,ms2=0.f,ms3=0.f;       // masked sum
        float q0=0.f,q1=0.f,q2=0.f,q3=0.f;           // masked sumsq
        float i0=1e30f,i1=1e30f,i2=1e30f,i3=1e30f;   // masked min
        float a0=-1e30f,a1=-1e30f,a2=-1e30f,a3=-1e30f; // masked max

        #pragma unroll 4
        for (int j = jb; j < NN; j += 16) {
            float4 v = *(const float4*)(Erow + (size_t)j * DE + 4 * dq);
            float mk = m_lds[j];
            s0 += v.x; s1 += v.y; s2 += v.z; s3 += v.w;
            ms0 = fmaf(mk, v.x, ms0); ms1 = fmaf(mk, v.y, ms1);
            ms2 = fmaf(mk, v.z, ms2); ms3 = fmaf(mk, v.w, ms3);
            q0 = fmaf(mk * v.x, v.x, q0); q1 = fmaf(mk * v.y, v.y, q1);
            q2 = fmaf(mk * v.z, v.z, q2); q3 = fmaf(mk * v.w, v.w, q3);
            bool on = (mk != 0.0f);
            i0 = fminf(i0, on ? v.x :  1e30f); i1 = fminf(i1, on ? v.y :  1e30f);
            i2 = fminf(i2, on ? v.z :  1e30f); i3 = fminf(i3, on ? v.w :  1e30f);
            a0 = fmaxf(a0, on ? v.x : -1e30f); a1 = fmaxf(a1, on ? v.y : -1e30f);
            a2 = fmaxf(a2, on ? v.z : -1e30f); a3 = fmaxf(a3, on ? v.w : -1e30f);
        }

        // butterfly reduce across the 4 j-groups within this wave
        #define RED_ADD(x) { x += __shfl_xor(x, 16); x += __shfl_xor(x, 32); }
        #define RED_MIN(x) { x = fminf(x, __shfl_xor(x, 16)); x = fminf(x, __shfl_xor(x, 32)); }
        #define RED_MAX(x) { x = fmaxf(x, __shfl_xor(x, 16)); x = fmaxf(x, __shfl_xor(x, 32)); }
        RED_ADD(s0) RED_ADD(s1) RED_ADD(s2) RED_ADD(s3)
        RED_ADD(ms0) RED_ADD(ms1) RED_ADD(ms2) RED_ADD(ms3)
        RED_ADD(q0) RED_ADD(q1) RED_ADD(q2) RED_ADD(q3)
        RED_MIN(i0) RED_MIN(i1) RED_MIN(i2) RED_MIN(i3)
        RED_MAX(a0) RED_MAX(a1) RED_MAX(a2) RED_MAX(a3)
        #undef RED_ADD
        #undef RED_MIN
        #undef RED_MAX

        if (lane < 16) {
            float* p = partial[wv][lane];
            p[0]=s0; p[1]=s1; p[2]=s2; p[3]=s3;
            p[4]=ms0; p[5]=ms1; p[6]=ms2; p[7]=ms3;
            p[8]=q0; p[9]=q1; p[10]=q2; p[11]=q3;
            p[12]=i0; p[13]=i1; p[14]=i2; p[15]=i3;
            p[16]=a0; p[17]=a1; p[18]=a2; p[19]=a3;
        }
        __syncthreads();

        if (t < 64) {
            const int d = t, dq2 = d >> 2, c = d & 3;
            float s = 0.f, ms = 0.f, mq = 0.f, lmi = 1e30f, lma = -1e30f;
            #pragma unroll
            for (int w = 0; w < 4; ++w) {
                const float* p = partial[w][dq2];
                s   += p[c];
                ms  += p[4 + c];
                mq  += p[8 + c];
                lmi  = fminf(lmi, p[12 + c]);
                lma  = fmaxf(lma, p[16 + c]);
            }
            float m    = s * inv_cnt;
            float stdv = mq * inv_cnt - 2.0f * m * (ms * inv_cnt) + m * m;
            z_lds[r][d]       = m;
            z_lds[r][64 + d]  = lmi;
            z_lds[r][128 + d] = lma;
            z_lds[r][192 + d] = stdv;
        }
        __syncthreads();  // protect partial[] reuse next row / z_lds complete
    }

    // ---- phase 2: matvec, thread t = dx ----
    float acc0, acc1, acc2, acc3;
    {
        float bv = bias[t];
        acc0 = bv; acc1 = bv; acc2 = bv; acc3 = bv;
    }
    const float4* Wrow = (const float4*)(W + (size_t)t * 4 * DE);
    #pragma unroll 8
    for (int f4 = 0; f4 < 64; ++f4) {
        float4 w4 = Wrow[f4];
        int f = 4 * f4;
        acc0 += z_lds[0][f]*w4.x + z_lds[0][f+1]*w4.y + z_lds[0][f+2]*w4.z + z_lds[0][f+3]*w4.w;
        acc1 += z_lds[1][f]*w4.x + z_lds[1][f+1]*w4.y + z_lds[1][f+2]*w4.z + z_lds[1][f+3]*w4.w;
        acc2 += z_lds[2][f]*w4.x + z_lds[2][f+1]*w4.y + z_lds[2][f+2]*w4.z + z_lds[2][f+3]*w4.w;
        acc3 += z_lds[3][f]*w4.x + z_lds[3][f+1]*w4.y + z_lds[3][f+2]*w4.z + z_lds[3][f+3]*w4.w;
    }
    out[(size_t)(g0 + 0) * DXX + t] = acc0;
    out[(size_t)(g0 + 1) * DXX + t] = acc1;
    out[(size_t)(g0 + 2) * DXX + t] = acc2;
    out[(size_t)(g0 + 3) * DXX + t] = acc3;
}

extern "C" void kernel_launch(void* const* d_in, const int* in_sizes, int n_in,
                              void* d_out, int out_size, void* d_ws, size_t ws_size,
                              hipStream_t stream) {
    const float*   E    = (const float*)d_in[0];
    const uint8_t* mraw = (const uint8_t*)d_in[1];
    const float*   W    = (const float*)d_in[2];
    const float*   bias = (const float*)d_in[3];
    float*         out  = (float*)d_out;
    float*         maskf = (float*)d_ws;   // 4096 floats = 16 KB

    mask_prep<<<1, 256, 0, stream>>>(mraw, maskf);
    etox_main<<<(BSZ * NN) / IB, 256, 0, stream>>>(E, maskf, W, bias, out);
}

// Round 2
// 71.391 us; speedup vs baseline: 1.1941x; 1.1941x over previous
//
#include <hip/hip_runtime.h>
#include <cstdint>
#include <cstddef>

#define BSZ 16
#define NN  256
#define DE  64
#define DXX 256
#define IB  4   // rows (b,i) per block

// Single fused kernel. Per block: IB=4 rows (b,i) of E (4 x 64 KB contiguous).
// Phase A: detect mask dtype (u8/i32/f32) from first 4096 bytes (per-block,
//          redundant, L2-served), load mask row for batch b, popcount.
// Phase B: one-pass j-reduction per row with depth-2 software-pipelined
//          float4 loads (4 KB/wave always in flight, incl. across barriers).
// Phase C: z (256 f) x W^T (256x256) matvec, thread t = dx, 4 rows.
__global__ __launch_bounds__(256, 4) void etox_fused(
    const float* __restrict__ E, const uint8_t* __restrict__ raw,
    const float* __restrict__ W, const float* __restrict__ bias,
    float* __restrict__ out)
{
    __shared__ float m_lds[NN];
    __shared__ int   det[2];
    __shared__ float cpart[4];
    __shared__ float partial[4][16][20];   // [wave][dquad][acc]
    __shared__ float z_lds[IB][4 * DE];

    const int t   = threadIdx.x;
    const int g0  = blockIdx.x * IB;       // global row = b*NN + i
    const int b   = g0 >> 8;

    // ---- phase A: mask dtype detection + mask row ----
    if (t == 0) { det[0] = 0; det[1] = 0; }
    int s1 = 0, s23 = 0;
    {
        const uint8_t* p = raw + t * 16;
        #pragma unroll
        for (int u = 0; u < 16; ++u) {
            int v = (int)p[u];
            int m4 = u & 3;                 // (t*16+u)&3 == u&3
            if (m4 == 1) s1 += v; else if (m4 >= 2) s23 += v;
        }
    }
    __syncthreads();                        // det init visible
    if (s1)  atomicAdd(&det[0], s1);
    if (s23) atomicAdd(&det[1], s23);
    __syncthreads();
    // i32: bytes %4 in {1,2,3} zero -> det[1]==0 (det[0]==0 too, order matters)
    // f32: byte %4==1 zero, %4 in {2,3} nonzero (0x3f800000 pattern)
    const int kind = (det[1] == 0) ? 1 : ((det[0] == 0) ? 2 : 0);

    float mv;
    {
        int idx = b * NN + t;
        if (kind == 1)      mv = (((const int*)(const void*)raw)[idx] != 0) ? 1.f : 0.f;
        else if (kind == 2) mv = (((const float*)(const void*)raw)[idx] != 0.f) ? 1.f : 0.f;
        else                mv = (raw[idx] != 0) ? 1.f : 0.f;
    }
    m_lds[t] = mv;
    unsigned long long bal = __ballot(mv != 0.f);
    const int wv = t >> 6, lane = t & 63;
    if (lane == 0) cpart[wv] = (float)__popcll(bal);
    __syncthreads();
    const float inv_cnt = 1.0f / (cpart[0] + cpart[1] + cpart[2] + cpart[3]);

    // ---- phase B: pipelined one-pass reductions ----
    const int dq = t & 15;                 // d = 4*dq .. 4*dq+3
    const int jb = t >> 4;                 // j = jb + 16*k, k = 0..15
    const float* base0 = E + (size_t)g0 * (NN * DE) + (size_t)jb * DE + 4 * dq;

    #define LD(P, K) (*(const float4*)((P) + (size_t)(K) * (16 * DE)))
    float4 A0, A1, A2, A3, B0, B1, B2, B3;
    A0 = LD(base0, 0); A1 = LD(base0, 1); A2 = LD(base0, 2); A3 = LD(base0, 3);

    for (int r = 0; r < IB; ++r) {
        const float* baser = base0 + (size_t)r * (NN * DE);

        float s[4]  = {0.f, 0.f, 0.f, 0.f};
        float ms[4] = {0.f, 0.f, 0.f, 0.f};
        float q[4]  = {0.f, 0.f, 0.f, 0.f};
        float mi[4] = {1e30f, 1e30f, 1e30f, 1e30f};
        float ma[4] = {-1e30f, -1e30f, -1e30f, -1e30f};

        #define CONS1(V, KK) { \
            float mk = m_lds[jb + 16 * (KK)]; \
            bool on = (mk != 0.f); \
            float4 v = V; \
            s[0] += v.x; s[1] += v.y; s[2] += v.z; s[3] += v.w; \
            ms[0] = fmaf(mk, v.x, ms[0]); ms[1] = fmaf(mk, v.y, ms[1]); \
            ms[2] = fmaf(mk, v.z, ms[2]); ms[3] = fmaf(mk, v.w, ms[3]); \
            q[0] = fmaf(mk * v.x, v.x, q[0]); q[1] = fmaf(mk * v.y, v.y, q[1]); \
            q[2] = fmaf(mk * v.z, v.z, q[2]); q[3] = fmaf(mk * v.w, v.w, q[3]); \
            mi[0] = fminf(mi[0], on ? v.x : 1e30f); mi[1] = fminf(mi[1], on ? v.y : 1e30f); \
            mi[2] = fminf(mi[2], on ? v.z : 1e30f); mi[3] = fminf(mi[3], on ? v.w : 1e30f); \
            ma[0] = fmaxf(ma[0], on ? v.x : -1e30f); ma[1] = fmaxf(ma[1], on ? v.y : -1e30f); \
            ma[2] = fmaxf(ma[2], on ? v.z : -1e30f); ma[3] = fmaxf(ma[3], on ? v.w : -1e30f); \
        }

        B0 = LD(baser, 4);  B1 = LD(baser, 5);  B2 = LD(baser, 6);  B3 = LD(baser, 7);
        CONS1(A0, 0) CONS1(A1, 1) CONS1(A2, 2) CONS1(A3, 3)
        A0 = LD(baser, 8);  A1 = LD(baser, 9);  A2 = LD(baser, 10); A3 = LD(baser, 11);
        CONS1(B0, 4) CONS1(B1, 5) CONS1(B2, 6) CONS1(B3, 7)
        B0 = LD(baser, 12); B1 = LD(baser, 13); B2 = LD(baser, 14); B3 = LD(baser, 15);
        CONS1(A0, 8) CONS1(A1, 9) CONS1(A2, 10) CONS1(A3, 11)
        if (r < IB - 1) {   // prefetch next row's batch 0 across the barriers
            const float* basen = baser + (NN * DE);
            A0 = LD(basen, 0); A1 = LD(basen, 1); A2 = LD(basen, 2); A3 = LD(basen, 3);
        }
        CONS1(B0, 12) CONS1(B1, 13) CONS1(B2, 14) CONS1(B3, 15)
        #undef CONS1

        // butterfly reduce across the 4 j-groups within this wave
        #pragma unroll
        for (int c = 0; c < 4; ++c) {
            s[c]  += __shfl_xor(s[c], 16);  s[c]  += __shfl_xor(s[c], 32);
            ms[c] += __shfl_xor(ms[c], 16); ms[c] += __shfl_xor(ms[c], 32);
            q[c]  += __shfl_xor(q[c], 16);  q[c]  += __shfl_xor(q[c], 32);
            mi[c] = fminf(mi[c], __shfl_xor(mi[c], 16));
            mi[c] = fminf(mi[c], __shfl_xor(mi[c], 32));
            ma[c] = fmaxf(ma[c], __shfl_xor(ma[c], 16));
            ma[c] = fmaxf(ma[c], __shfl_xor(ma[c], 32));
        }

        if (lane < 16) {
            float* p = partial[wv][lane];
            #pragma unroll
            for (int c = 0; c < 4; ++c) {
                p[c]      = s[c];
                p[4 + c]  = ms[c];
                p[8 + c]  = q[c];
                p[12 + c] = mi[c];
                p[16 + c] = ma[c];
            }
        }
        __syncthreads();

        if (t < 64) {
            const int d = t, dq2 = d >> 2, c = d & 3;
            float ss = 0.f, mss = 0.f, mq = 0.f, lmi = 1e30f, lma = -1e30f;
            #pragma unroll
            for (int w = 0; w < 4; ++w) {
                const float* p = partial[w][dq2];
                ss  += p[c];
                mss += p[4 + c];
                mq  += p[8 + c];
                lmi  = fminf(lmi, p[12 + c]);
                lma  = fmaxf(lma, p[16 + c]);
            }
            float m    = ss * inv_cnt;
            float stdv = mq * inv_cnt - 2.0f * m * (mss * inv_cnt) + m * m;
            z_lds[r][d]       = m;
            z_lds[r][64 + d]  = lmi;
            z_lds[r][128 + d] = lma;
            z_lds[r][192 + d] = stdv;
        }
        __syncthreads();   // partial[] reuse next row / z_lds complete
    }
    #undef LD

    // ---- phase C: matvec, thread t = dx ----
    float acc0, acc1, acc2, acc3;
    {
        float bv = bias[t];
        acc0 = bv; acc1 = bv; acc2 = bv; acc3 = bv;
    }
    const float4* Wrow = (const float4*)(W + (size_t)t * 4 * DE);
    #pragma unroll 8
    for (int f4 = 0; f4 < 64; ++f4) {
        float4 w4 = Wrow[f4];
        int f = 4 * f4;
        acc0 += z_lds[0][f] * w4.x + z_lds[0][f+1] * w4.y + z_lds[0][f+2] * w4.z + z_lds[0][f+3] * w4.w;
        acc1 += z_lds[1][f] * w4.x + z_lds[1][f+1] * w4.y + z_lds[1][f+2] * w4.z + z_lds[1][f+3] * w4.w;
        acc2 += z_lds[2][f] * w4.x + z_lds[2][f+1] * w4.y + z_lds[2][f+2] * w4.z + z_lds[2][f+3] * w4.w;
        acc3 += z_lds[3][f] * w4.x + z_lds[3][f+1] * w4.y + z_lds[3][f+2] * w4.z + z_lds[3][f+3] * w4.w;
    }
    out[(size_t)(g0 + 0) * DXX + t] = acc0;
    out[(size_t)(g0 + 1) * DXX + t] = acc1;
    out[(size_t)(g0 + 2) * DXX + t] = acc2;
    out[(size_t)(g0 + 3) * DXX + t] = acc3;
}

extern "C" void kernel_launch(void* const* d_in, const int* in_sizes, int n_in,
                              void* d_out, int out_size, void* d_ws, size_t ws_size,
                              hipStream_t stream) {
    const float*   E    = (const float*)d_in[0];
    const uint8_t* mraw = (const uint8_t*)d_in[1];
    const float*   W    = (const float*)d_in[2];
    const float*   bias = (const float*)d_in[3];
    float*         out  = (float*)d_out;

    etox_fused<<<(BSZ * NN) / IB, 256, 0, stream>>>(E, mraw, W, bias, out);
}